// Round 3
// baseline (616.707 us; speedup 1.0000x reference)
//
#include <hip/hip_runtime.h>

#define Cdim 128
#define Hdim 1024
#define Idim 512
#define Odim 128

#define BT 32      // batch tile rows per block (8 blocks per channel)
#define HS_LD 136  // Hs leading dim (read slot-balanced: 17 ≡ 1 mod 8)

typedef __attribute__((ext_vector_type(8))) short short8;
typedef __attribute__((ext_vector_type(4))) float f32x4;

#define FENCE() asm volatile("" ::: "memory")
#define BAR()   __builtin_amdgcn_s_barrier()
#define LGKM0() asm volatile("s_waitcnt lgkmcnt(0)" ::: "memory")

// fp32x8 -> bf16x8 (truncate; same numerics as previous rounds)
__device__ __forceinline__ short8 cvt8(float4 v0, float4 v1) {
    union { unsigned int u[4]; short8 s; } r;
    r.u[0] = __builtin_amdgcn_perm(__float_as_uint(v0.y), __float_as_uint(v0.x), 0x07060302);
    r.u[1] = __builtin_amdgcn_perm(__float_as_uint(v0.w), __float_as_uint(v0.z), 0x07060302);
    r.u[2] = __builtin_amdgcn_perm(__float_as_uint(v1.y), __float_as_uint(v1.x), 0x07060302);
    r.u[3] = __builtin_amdgcn_perm(__float_as_uint(v1.w), __float_as_uint(v1.z), 0x07060302);
    return r.s;
}

__global__ __launch_bounds__(256, 3) void mlp_fused(
    const float* __restrict__ x, const float* __restrict__ w1,
    const float* __restrict__ b1, const float* __restrict__ w2,
    const float* __restrict__ b2, float* __restrict__ out)
{
    // W1/X double-buffered, XOR-swizzled (LD=64, no pad). Hs separate. 49664 B total.
    __shared__ __align__(16) unsigned short W1d[2][128 * 64];  // 32768 B
    __shared__ __align__(16) unsigned short Xd [2][ 32 * 64];  //  8192 B
    __shared__ __align__(16) unsigned short Hsm[32 * HS_LD];   //  8704 B

    const int t    = threadIdx.x;
    const int lane = t & 63;
    const int q    = lane >> 4;   // quad 0..3
    const int r16  = lane & 15;
    const int wn   = t >> 6;      // wave 0..3 -> output col block (wn*32)

    // staging decomposition: 8 thr/row (32B fp32 each -> one 16B bf16 granule)
    const int tx8 = t & 7;
    const int tr  = t >> 3;       // 0..31

    // block mapping: bt fastest so the 8 same-c blocks are dispatch-adjacent
    // (co-resident on one XCD -> w1[c] fetched from HBM once, shared via L2)
    const int bid = blockIdx.x;
    const int xcd = bid & 7;
    const int sb  = bid >> 3;           // 0..127
    const int bt  = sb & 7;             // 0..7
    const int c   = xcd * 16 + (sb >> 3);
    const int row0 = bt * BT;

    const float* xtr  = x  + ((size_t)(row0 + tr) * Cdim + c) * Idim + tx8 * 8;
    const float* w1tr = w1 + ((size_t)c * Hdim + tr) * Idim + tx8 * 8;
    const float* w2r0 = w2 + ((size_t)c * Odim + wn * 32 + r16) * Hdim + q * 8;

    // XOR swizzle: 16B granule (8 shorts) index ^= (row & 7)
    const int colw = (tx8 * 8) ^ ((tr & 7) << 3);   // write-side swizzled col
    const int swR  = (r16 & 7) << 3;                // read-side XOR mask

    // persistent layer-2 accumulators, init with b2 broadcast
    f32x4 acc2[2][2];
    #pragma unroll
    for (int j = 0; j < 2; ++j) {
        float bv = b2[c * Odim + wn * 32 + j * 16 + r16];
        f32x4 z = {bv, bv, bv, bv};
        acc2[0][j] = z;
        acc2[1][j] = z;
    }

    float4 pw[8], px[2];   // 1-phase-ahead staging registers

#define ISSUE(ht2, kt2) do {                                                     \
        const float* _wp = w1tr + ((size_t)(ht2) * 128 * Idim) + (kt2) * 64;     \
        pw[0] = *(const float4*)(_wp);             pw[1] = *(const float4*)(_wp + 4);             \
        pw[2] = *(const float4*)(_wp + 32 * Idim); pw[3] = *(const float4*)(_wp + 32 * Idim + 4); \
        pw[4] = *(const float4*)(_wp + 64 * Idim); pw[5] = *(const float4*)(_wp + 64 * Idim + 4); \
        pw[6] = *(const float4*)(_wp + 96 * Idim); pw[7] = *(const float4*)(_wp + 96 * Idim + 4); \
        const float* _xp = xtr + (kt2) * 64;                                     \
        px[0] = *(const float4*)(_xp);             px[1] = *(const float4*)(_xp + 4);             \
    } while (0)

#define WRITE_TILE(nb) do {                                                      \
        unsigned short* _w = &W1d[nb][0];                                        \
        *(short8*)&_w[(tr     ) * 64 + colw] = cvt8(pw[0], pw[1]);               \
        *(short8*)&_w[(tr + 32) * 64 + colw] = cvt8(pw[2], pw[3]);               \
        *(short8*)&_w[(tr + 64) * 64 + colw] = cvt8(pw[4], pw[5]);               \
        *(short8*)&_w[(tr + 96) * 64 + colw] = cvt8(pw[6], pw[7]);               \
        *(short8*)&Xd[nb][tr * 64 + colw] = cvt8(px[0], px[1]);                  \
    } while (0)

    // prologue: tile 0 staged, tile 1 in regs
    ISSUE(0, 0);
    WRITE_TILE(0);
    ISSUE(0, 1);
    FENCE(); LGKM0(); BAR(); FENCE();

    for (int ht = 0; ht < 8; ++ht) {
        f32x4 acc1[2][2];
        #pragma unroll
        for (int i = 0; i < 2; ++i)
            #pragma unroll
            for (int j = 0; j < 2; ++j) acc1[i][j] = (f32x4){0.f, 0.f, 0.f, 0.f};

        #pragma unroll 2
        for (int kt = 0; kt < 8; ++kt) {
            const int g   = ht * 8 + kt;
            const int cur = kt & 1;
            const int nxt = cur ^ 1;
            // stage tile g+1 (in regs) into the other buffer
            if (g <= 62) WRITE_TILE(nxt);
            // issue tile g+2 loads — they fly across the next barrier(s)
            if (g <= 61) { const int g2 = g + 2; ISSUE(g2 >> 3, g2 & 7); }
            // compute tile g from current buffer
            #pragma unroll
            for (int ks = 0; ks < 2; ++ks) {
                const int col = (ks * 32 + q * 8) ^ swR;
                short8 a0  = *(const short8*)&Xd[cur][ r16       * 64 + col];
                short8 a1  = *(const short8*)&Xd[cur][(r16 + 16) * 64 + col];
                short8 b0  = *(const short8*)&W1d[cur][(wn * 32 + r16     ) * 64 + col];
                short8 b1f = *(const short8*)&W1d[cur][(wn * 32 + r16 + 16) * 64 + col];
                acc1[0][0] = __builtin_amdgcn_mfma_f32_16x16x32_bf16(a0, b0,  acc1[0][0], 0, 0, 0);
                acc1[0][1] = __builtin_amdgcn_mfma_f32_16x16x32_bf16(a0, b1f, acc1[0][1], 0, 0, 0);
                acc1[1][0] = __builtin_amdgcn_mfma_f32_16x16x32_bf16(a1, b0,  acc1[1][0], 0, 0, 0);
                acc1[1][1] = __builtin_amdgcn_mfma_f32_16x16x32_bf16(a1, b1f, acc1[1][1], 0, 0, 0);
            }
            // single barrier: my ds_reads done (lgkm) + my ds_writes visible
            FENCE(); LGKM0(); BAR(); FENCE();
        }

        // ---- ht boundary ----
        // issue W2 ks=0 fragments (global, L2/L3-resident) — fly during epilogue
        const float* wr = w2r0 + ht * 128;
        float4 pb0a = *(const float4*)(wr);
        float4 pb0b = *(const float4*)(wr + 4);
        float4 pb1a = *(const float4*)(wr + 16 * Hdim);
        float4 pb1b = *(const float4*)(wr + 16 * Hdim + 4);
        const float b1v0 = b1[c * Hdim + ht * 128 + wn * 32 + r16];
        const float b1v1 = b1[c * Hdim + ht * 128 + wn * 32 + 16 + r16];

        // epilogue: Hs = bf16(relu(acc1 + b1))
        #pragma unroll
        for (int j = 0; j < 2; ++j) {
            const float bv = j ? b1v1 : b1v0;
            const int n = wn * 32 + j * 16 + r16;
            #pragma unroll
            for (int i = 0; i < 2; ++i)
                #pragma unroll
                for (int r = 0; r < 4; ++r) {
                    const int m = i * 16 + q * 4 + r;
                    const float hv = fmaxf(acc1[i][j][r] + bv, 0.f);
                    Hsm[m * HS_LD + n] = (unsigned short)(__float_as_uint(hv) >> 16);
                }
        }
        FENCE(); LGKM0(); BAR(); FENCE();

        // layer 2: acc2 += Hs(32x128) * W2^T, W2 frags direct from global, 1-ks-ahead
        #pragma unroll
        for (int ks = 0; ks < 4; ++ks) {
            short8 bb0 = cvt8(pb0a, pb0b);
            short8 bb1 = cvt8(pb1a, pb1b);
            if (ks < 3) {
                const float* wnx = wr + (ks + 1) * 32;
                pb0a = *(const float4*)(wnx);
                pb0b = *(const float4*)(wnx + 4);
                pb1a = *(const float4*)(wnx + 16 * Hdim);
                pb1b = *(const float4*)(wnx + 16 * Hdim + 4);
            }
            const int hcol = ks * 32 + q * 8;
            short8 a0 = *(const short8*)&Hsm[ r16       * HS_LD + hcol];
            short8 a1 = *(const short8*)&Hsm[(r16 + 16) * HS_LD + hcol];
            acc2[0][0] = __builtin_amdgcn_mfma_f32_16x16x32_bf16(a0, bb0, acc2[0][0], 0, 0, 0);
            acc2[0][1] = __builtin_amdgcn_mfma_f32_16x16x32_bf16(a0, bb1, acc2[0][1], 0, 0, 0);
            acc2[1][0] = __builtin_amdgcn_mfma_f32_16x16x32_bf16(a1, bb0, acc2[1][0], 0, 0, 0);
            acc2[1][1] = __builtin_amdgcn_mfma_f32_16x16x32_bf16(a1, bb1, acc2[1][1], 0, 0, 0);
        }
        // no barrier needed: next phase touches only W1d/Xd (last read before
        // phase-7's barrier); Hs WAR is covered by the 8 phase barriers.
    }

    // store: out[b, o, c] — XCD swizzle groups the 16 c-writers of each 64B line
    #pragma unroll
    for (int i = 0; i < 2; ++i)
        #pragma unroll
        for (int j = 0; j < 2; ++j)
            #pragma unroll
            for (int r = 0; r < 4; ++r) {
                const int bb = row0 + i * 16 + q * 4 + r;
                const int o  = wn * 32 + j * 16 + r16;
                out[(size_t)bb * (Odim * Cdim) + o * Cdim + c] = acc2[i][j][r];
            }
#undef ISSUE
#undef WRITE_TILE
}

extern "C" void kernel_launch(void* const* d_in, const int* in_sizes, int n_in,
                              void* d_out, int out_size, void* d_ws, size_t ws_size,
                              hipStream_t stream) {
    const float* x  = (const float*)d_in[0];
    const float* w1 = (const float*)d_in[1];
    const float* b1 = (const float*)d_in[2];
    const float* w2 = (const float*)d_in[3];
    const float* b2 = (const float*)d_in[4];
    float* out = (float*)d_out;
    mlp_fused<<<dim3(1024), dim3(256), 0, stream>>>(x, w1, b1, w2, b2, out);
}

// Round 5
// 569.765 us; speedup vs baseline: 1.0824x; 1.0824x over previous
//
#include <hip/hip_runtime.h>

#define Cdim 128
#define Hdim 1024
#define Idim 512
#define Odim 128

typedef __attribute__((ext_vector_type(8))) short short8;
typedef __attribute__((ext_vector_type(4))) float f32x4;

#define FENCE() asm volatile("" ::: "memory")
#define BAR()   __builtin_amdgcn_s_barrier()
#define LGKM0() asm volatile("s_waitcnt lgkmcnt(0)" ::: "memory")
#define VM0()   asm volatile("s_waitcnt vmcnt(0)" ::: "memory")

// fp32x8 -> bf16x8 (truncate; same numerics as all previous rounds)
__device__ __forceinline__ short8 cvt8(float4 v0, float4 v1) {
    union { unsigned int u[4]; short8 s; } r;
    r.u[0] = __builtin_amdgcn_perm(__float_as_uint(v0.y), __float_as_uint(v0.x), 0x07060302);
    r.u[1] = __builtin_amdgcn_perm(__float_as_uint(v0.w), __float_as_uint(v0.z), 0x07060302);
    r.u[2] = __builtin_amdgcn_perm(__float_as_uint(v1.y), __float_as_uint(v1.x), 0x07060302);
    r.u[3] = __builtin_amdgcn_perm(__float_as_uint(v1.w), __float_as_uint(v1.z), 0x07060302);
    return r.s;
}

// async global->LDS, 16B per lane, zero VGPR staging
__device__ __forceinline__ void dma16(const float* g, float* l) {
    __builtin_amdgcn_global_load_lds(
        (const __attribute__((address_space(1))) unsigned int*)g,
        (__attribute__((address_space(3))) unsigned int*)l, 16, 0, 0);
}

__global__ __launch_bounds__(256, 2) void mlp_fused(
    const float* __restrict__ x, const float* __restrict__ w1,
    const float* __restrict__ b1, const float* __restrict__ w2,
    const float* __restrict__ b2, float* __restrict__ out)
{
    // All staging in fp32 via DMA; 16B-granule XOR-swizzled by source address.
    __shared__ __align__(16) float W1f[2][128 * 32];       // 32768 B (W1 and W2 tiles)
    __shared__ __align__(16) float Xf [2][64 * 32];        // 16384 B
    __shared__ __align__(16) unsigned short Hs[64 * 128];  // 16384 B, granule-swizzled
    // total = 65536 B -> 2 blocks/CU

    const int t    = threadIdx.x;
    const int lane = t & 63;
    const int q    = lane >> 4;   // 0..3
    const int r16  = lane & 15;
    const int wave = t >> 6;      // 0..3
    const int wm   = wave >> 1;
    const int wn   = wave & 1;
    const int l8   = lane & 7;    // granule slot within 8-row segment
    const int lr   = lane >> 3;   // row within segment (== row&7 for 8-aligned rows)
    const int gsw  = l8 ^ lr;     // source granule swizzle (rule #21: swizzle src, LDS linear)

    // bt-fastest mapping: the 4 same-c blocks are dispatch-adjacent on one XCD
    const int bid  = blockIdx.x;
    const int xcd  = bid & 7;
    const int s    = bid >> 3;          // 0..63
    const int bt   = s & 3;
    const int c    = xcd * 16 + (s >> 2);
    const int row0 = bt * 64;

    const float* w1c = w1 + (size_t)c * Hdim * Idim;
    const float* w2c = w2 + (size_t)c * Odim * Hdim;

    // per-lane DMA source bases (each dma16 covers 8 rows x 128B)
    const float* w1src = w1c + (size_t)(wave * 32 + lr) * Idim + gsw * 4;
    const float* w2src = w2c + (size_t)(wave * 32 + lr) * Hdim + gsw * 4;
    const float* xsrc  = x + ((size_t)(row0 + wave * 16 + lr) * Cdim + c) * Idim + gsw * 4;
    const size_t xst8  = (size_t)8 * Cdim * Idim;

    // fragment-read constants: granule offsets are lane-constant (s7 = row&7 of all frag rows)
    const int s7    = r16 & 7;
    const int offLo = ((2 * q)     ^ s7) << 2;   // float index within 32-float row
    const int offHi = ((2 * q + 1) ^ s7) << 2;
    const int aRow0 = (wm * 32 +      r16) * 32;
    const int aRow1 = (wm * 32 + 16 + r16) * 32;
    const int bRow0 = (wn * 64 +      r16) * 32;
    const int bRow1 = (wn * 64 + 16 + r16) * 32;
    const int bRow2 = (wn * 64 + 32 + r16) * 32;
    const int bRow3 = (wn * 64 + 48 + r16) * 32;

    f32x4 acc2[2][4];
    #pragma unroll
    for (int j = 0; j < 4; ++j) {
        float bv = b2[c * Odim + wn * 64 + j * 16 + r16];
        f32x4 z = {bv, bv, bv, bv};
        acc2[0][j] = z;
        acc2[1][j] = z;
    }

#define ISSUE_W1(ht2, kt2) do { const int _nb = (kt2) & 1;                       \
        const float* _ws = w1src + (size_t)((ht2) * 128) * Idim + (kt2) * 32;    \
        float* _wd = &W1f[_nb][wave * 32 * 32];                                  \
        dma16(_ws,             _wd);                                             \
        dma16(_ws +  8 * Idim, _wd +  8 * 32);                                   \
        dma16(_ws + 16 * Idim, _wd + 16 * 32);                                   \
        dma16(_ws + 24 * Idim, _wd + 24 * 32);                                   \
        const float* _xs = xsrc + (kt2) * 32;                                    \
        float* _xd = &Xf[_nb][wave * 16 * 32];                                   \
        dma16(_xs,        _xd);                                                  \
        dma16(_xs + xst8, _xd + 8 * 32);                                         \
    } while (0)

#define ISSUE_W2(ht2, ks2) do { const int _nb = (ks2) & 1;                       \
        const float* _vs = w2src + (ht2) * 128 + (ks2) * 32;                     \
        float* _vd = &W1f[_nb][wave * 32 * 32];                                  \
        dma16(_vs,             _vd);                                             \
        dma16(_vs +  8 * Hdim, _vd +  8 * 32);                                   \
        dma16(_vs + 16 * Hdim, _vd + 16 * 32);                                   \
        dma16(_vs + 24 * Hdim, _vd + 24 * 32);                                   \
    } while (0)

    ISSUE_W1(0, 0);   // prologue: tile 0 in flight

    for (int ht = 0; ht < 8; ++ht) {
        f32x4 acc1[2][4];
        #pragma unroll
        for (int i = 0; i < 2; ++i)
            #pragma unroll
            for (int j = 0; j < 4; ++j) acc1[i][j] = (f32x4){0.f, 0.f, 0.f, 0.f};

        #pragma unroll 2
        for (int kt = 0; kt < 16; ++kt) {
            VM0();            // own 6 DMA of tile kt done (only thing outstanding)
            BAR();            // all waves' segments visible; prev buf reads done
            FENCE();
            if (kt < 15) ISSUE_W1(ht, kt + 1);
            else         ISSUE_W2(ht, 0);
            FENCE();
            const int cur = kt & 1;
            const float* Wb = W1f[cur];
            const float* Xb = Xf[cur];
            short8 a0  = cvt8(*(const float4*)(Xb + aRow0 + offLo), *(const float4*)(Xb + aRow0 + offHi));
            short8 a1  = cvt8(*(const float4*)(Xb + aRow1 + offLo), *(const float4*)(Xb + aRow1 + offHi));
            short8 f0  = cvt8(*(const float4*)(Wb + bRow0 + offLo), *(const float4*)(Wb + bRow0 + offHi));
            short8 f1  = cvt8(*(const float4*)(Wb + bRow1 + offLo), *(const float4*)(Wb + bRow1 + offHi));
            short8 f2  = cvt8(*(const float4*)(Wb + bRow2 + offLo), *(const float4*)(Wb + bRow2 + offHi));
            short8 f3  = cvt8(*(const float4*)(Wb + bRow3 + offLo), *(const float4*)(Wb + bRow3 + offHi));
            acc1[0][0] = __builtin_amdgcn_mfma_f32_16x16x32_bf16(a0, f0, acc1[0][0], 0, 0, 0);
            acc1[0][1] = __builtin_amdgcn_mfma_f32_16x16x32_bf16(a0, f1, acc1[0][1], 0, 0, 0);
            acc1[0][2] = __builtin_amdgcn_mfma_f32_16x16x32_bf16(a0, f2, acc1[0][2], 0, 0, 0);
            acc1[0][3] = __builtin_amdgcn_mfma_f32_16x16x32_bf16(a0, f3, acc1[0][3], 0, 0, 0);
            acc1[1][0] = __builtin_amdgcn_mfma_f32_16x16x32_bf16(a1, f0, acc1[1][0], 0, 0, 0);
            acc1[1][1] = __builtin_amdgcn_mfma_f32_16x16x32_bf16(a1, f1, acc1[1][1], 0, 0, 0);
            acc1[1][2] = __builtin_amdgcn_mfma_f32_16x16x32_bf16(a1, f2, acc1[1][2], 0, 0, 0);
            acc1[1][3] = __builtin_amdgcn_mfma_f32_16x16x32_bf16(a1, f3, acc1[1][3], 0, 0, 0);
        }

        // ---- ht boundary: epilogue layer 1 into swizzled Hs ----
        const int hb = c * Hdim + ht * 128;
        const float bva[4] = { b1[hb + wn * 64 + r16],      b1[hb + wn * 64 + 16 + r16],
                               b1[hb + wn * 64 + 32 + r16], b1[hb + wn * 64 + 48 + r16] };
        #pragma unroll
        for (int j = 0; j < 4; ++j) {
            const int n = wn * 64 + j * 16 + r16;
            #pragma unroll
            for (int i = 0; i < 2; ++i)
                #pragma unroll
                for (int r = 0; r < 4; ++r) {
                    const int m = wm * 32 + i * 16 + q * 4 + r;
                    const float hv = fmaxf(acc1[i][j][r] + bva[j], 0.f);
                    Hs[m * 128 + (((n >> 3) ^ (m & 7)) << 3) + (n & 7)] =
                        (unsigned short)(__float_as_uint(hv) >> 16);
                }
        }
        LGKM0();   // Hs writes drained before the publishing barrier below

        // ---- 4 W2 phases: same machinery, B-tiles from W1f buffers ----
        #pragma unroll
        for (int ks = 0; ks < 4; ++ks) {
            VM0();
            BAR();
            FENCE();
            if (ks < 3)      ISSUE_W2(ht, ks + 1);
            else if (ht < 7) ISSUE_W1(ht + 1, 0);
            FENCE();
            const int cur = ks & 1;
            const float* Wb = W1f[cur];
            const int goff = ((ks * 4 + q) ^ s7) << 3;   // Hs granule (swizzled)
            short8 a0 = *(const short8*)&Hs[(wm * 32 +      r16) * 128 + goff];
            short8 a1 = *(const short8*)&Hs[(wm * 32 + 16 + r16) * 128 + goff];
            short8 f0 = cvt8(*(const float4*)(Wb + bRow0 + offLo), *(const float4*)(Wb + bRow0 + offHi));
            short8 f1 = cvt8(*(const float4*)(Wb + bRow1 + offLo), *(const float4*)(Wb + bRow1 + offHi));
            short8 f2 = cvt8(*(const float4*)(Wb + bRow2 + offLo), *(const float4*)(Wb + bRow2 + offHi));
            short8 f3 = cvt8(*(const float4*)(Wb + bRow3 + offLo), *(const float4*)(Wb + bRow3 + offHi));
            acc2[0][0] = __builtin_amdgcn_mfma_f32_16x16x32_bf16(a0, f0, acc2[0][0], 0, 0, 0);
            acc2[0][1] = __builtin_amdgcn_mfma_f32_16x16x32_bf16(a0, f1, acc2[0][1], 0, 0, 0);
            acc2[0][2] = __builtin_amdgcn_mfma_f32_16x16x32_bf16(a0, f2, acc2[0][2], 0, 0, 0);
            acc2[0][3] = __builtin_amdgcn_mfma_f32_16x16x32_bf16(a0, f3, acc2[0][3], 0, 0, 0);
            acc2[1][0] = __builtin_amdgcn_mfma_f32_16x16x32_bf16(a1, f0, acc2[1][0], 0, 0, 0);
            acc2[1][1] = __builtin_amdgcn_mfma_f32_16x16x32_bf16(a1, f1, acc2[1][1], 0, 0, 0);
            acc2[1][2] = __builtin_amdgcn_mfma_f32_16x16x32_bf16(a1, f2, acc2[1][2], 0, 0, 0);
            acc2[1][3] = __builtin_amdgcn_mfma_f32_16x16x32_bf16(a1, f3, acc2[1][3], 0, 0, 0);
        }
    }

    // store: out[b, o, c] — XCD swizzle groups the 16 c-writers of each 64B line
    #pragma unroll
    for (int i = 0; i < 2; ++i)
        #pragma unroll
        for (int j = 0; j < 4; ++j)
            #pragma unroll
            for (int r = 0; r < 4; ++r) {
                const int bb = row0 + wm * 32 + i * 16 + q * 4 + r;
                const int o  = wn * 64 + j * 16 + r16;
                out[(size_t)bb * (Odim * Cdim) + o * Cdim + c] = acc2[i][j][r];
            }
#undef ISSUE_W1
#undef ISSUE_W2
}

extern "C" void kernel_launch(void* const* d_in, const int* in_sizes, int n_in,
                              void* d_out, int out_size, void* d_ws, size_t ws_size,
                              hipStream_t stream) {
    const float* x  = (const float*)d_in[0];
    const float* w1 = (const float*)d_in[1];
    const float* b1 = (const float*)d_in[2];
    const float* w2 = (const float*)d_in[3];
    const float* b2 = (const float*)d_in[4];
    float* out = (float*)d_out;
    mlp_fused<<<dim3(512), dim3(256), 0, stream>>>(x, w1, b1, w2, b2, out);
}